// Round 4
// baseline (130.893 us; speedup 1.0000x reference)
//
#include <hip/hip_runtime.h>

// LocalWindowAttention B=1 H=8 S=4096 D=128 WIN=256, fp32 in/out.
// QK^T: 3-term bf16 hi/lo split MFMA, K loaded global->reg (no LDS, no barriers).
// PV: bf16 MFMA, V^T staged in LDS (double-buffered, reg-prefetched).
// 1 block = 64 q-rows x 1 head; 4 waves x 16 rows; P wave-private in LDS.

typedef short  bf16x8 __attribute__((ext_vector_type(8)));
typedef __bf16 bf16v8 __attribute__((ext_vector_type(8)));
typedef float  f32x4  __attribute__((ext_vector_type(4)));

constexpr int QB = 64, DH = 128, WIN = 256, KT = 64;
constexpr int NTILE = 5, NSUB = 20;
constexpr float SCALE = 0.08838834764831844f;  // 1/sqrt(128)

// LDS map (bytes): P [0, 41984) = 64 rows x 328 bf16 (wave-private rows)
//                  V^T buf0 [43008, +16384), buf1 [59392, +16384)
constexpr int PSTR = 328;
constexpr int VT0  = 43008;
constexpr int VT1  = VT0 + 16384;
constexpr int SMEM_BYTES = VT1 + 16384;   // 75776 -> 2 blocks/CU

__device__ __forceinline__ short bf16_of(float x) {   // RNE
  union { float f; unsigned u; } a; a.f = x;
  unsigned r = a.u + 0x7fffu + ((a.u >> 16) & 1u);
  return (short)(r >> 16);
}
__device__ __forceinline__ float f_of(short s) {
  union { float f; unsigned u; } a; a.u = ((unsigned)(unsigned short)s) << 16;
  return a.f;
}
__device__ __forceinline__ bf16v8 as_bf(bf16x8 s) {
  union { bf16x8 s; bf16v8 b; } u; u.s = s; return u.b;
}
#define MFMA(A, B, C) __builtin_amdgcn_mfma_f32_16x16x32_bf16(as_bf(A), as_bf(B), (C), 0, 0, 0)

__global__ __launch_bounds__(256, 2)
void lwa3(const float* __restrict__ qg, const float* __restrict__ kg,
          const float* __restrict__ vg, float* __restrict__ og, int S) {
  __shared__ __align__(16) char smem[SMEM_BYTES];

  const int bid = blockIdx.x;
  const int h   = bid & 7;              // head -> XCD round-robin (L2 locality)
  const int q0  = (bid >> 3) * QB;
  const int tid = threadIdx.x;
  const int wv  = tid >> 6;
  const int lane = tid & 63;
  const int lg  = lane >> 4;
  const int lm  = lane & 15;

  const float* qgb = qg + (size_t)h * S * DH;
  const float* kgb = kg + (size_t)h * S * DH;
  const float* vgb = vg + (size_t)h * S * DH;

  // ---- Q fragments: global -> reg, scaled, hi/lo split. A-frag row=lm, k=32kc+8lg+j ----
  bf16x8 qhi[4], qlo[4];
  {
    const float* qrow = qgb + (size_t)(q0 + 16 * wv + lm) * DH;
#pragma unroll
    for (int kc = 0; kc < 4; ++kc) {
      const int d0 = 32 * kc + 8 * lg;
      float4 a = *(const float4*)(qrow + d0);
      float4 b = *(const float4*)(qrow + d0 + 4);
      float x[8] = {a.x, a.y, a.z, a.w, b.x, b.y, b.z, b.w};
      bf16x8 hi, lo;
#pragma unroll
      for (int j = 0; j < 8; ++j) {
        float xs = x[j] * SCALE;
        short hs = bf16_of(xs);
        hi[j] = hs;
        lo[j] = bf16_of(xs - f_of(hs));
      }
      qhi[kc] = hi; qlo[kc] = lo;
    }
  }

  f32x4 acc[NSUB];
#pragma unroll
  for (int t = 0; t < NSUB; ++t) acc[t] = (f32x4){0.f, 0.f, 0.f, 0.f};

  // ---- pass 1: S = Q K^T, K B-frags direct from global (no LDS, no barriers) ----
  // B-frag: key = 16n+lm, d = 32kc+8lg..+7  (wave-independent -> L1-shared)
#pragma unroll
  for (int t = 0; t < NTILE; ++t) {
    const int kt0 = q0 - WIN + t * KT;
    if (kt0 < 0) continue;                       // block-uniform
#pragma unroll
    for (int n = 0; n < 4; ++n) {
      const float* krow = kgb + (size_t)(kt0 + 16 * n + lm) * DH;
      float4 kfa[4], kfb[4];
#pragma unroll
      for (int kc = 0; kc < 4; ++kc) {
        const int d0 = 32 * kc + 8 * lg;
        kfa[kc] = *(const float4*)(krow + d0);
        kfb[kc] = *(const float4*)(krow + d0 + 4);
      }
      f32x4 c = acc[4 * t + n];
#pragma unroll
      for (int kc = 0; kc < 4; ++kc) {
        float x[8] = {kfa[kc].x, kfa[kc].y, kfa[kc].z, kfa[kc].w,
                      kfb[kc].x, kfb[kc].y, kfb[kc].z, kfb[kc].w};
        bf16x8 kh, kl;
#pragma unroll
        for (int j = 0; j < 8; ++j) {
          short hs = bf16_of(x[j]);
          kh[j] = hs;
          kl[j] = bf16_of(x[j] - f_of(hs));
        }
        c = MFMA(qhi[kc], kh, c);
        c = MFMA(qlo[kc], kh, c);
        c = MFMA(qhi[kc], kl, c);
      }
      acc[4 * t + n] = c;
    }
  }

  // ---- V staging helpers ----
  const int srow = tid >> 4;          // 0..15
  const int sd0  = (tid & 15) * 8;    // first d of 8
  auto vload = [&](int kt0, float4 r[8]) {
#pragma unroll
    for (int i = 0; i < 4; ++i) {
      const float* p = vgb + (size_t)(kt0 + srow + 16 * i) * DH + sd0;
      r[2 * i]     = *(const float4*)(p);
      r[2 * i + 1] = *(const float4*)(p + 4);
    }
  };
  auto vwrite = [&](char* dst, const float4 r[8]) {
#pragma unroll
    for (int i = 0; i < 4; ++i) {
      const int key = srow + 16 * i;
      float x[8] = {r[2*i].x, r[2*i].y, r[2*i].z, r[2*i].w,
                    r[2*i+1].x, r[2*i+1].y, r[2*i+1].z, r[2*i+1].w};
#pragma unroll
      for (int j = 0; j < 8; ++j) {
        const int d = sd0 + j;
        const int swz = ((d & 7) ^ ((d >> 3) & 7)) << 4;
        *(short*)(dst + d * 128 + ((key * 2) ^ swz)) = bf16_of(x[j]);
      }
    }
  };

  // issue V[0], V[1] global loads now: latency hides under softmax
  const int kt0_0 = q0 - WIN, kt0_1 = q0 - WIN + KT;
  float4 vr0[8], vr1[8];
  if (kt0_0 >= 0) vload(kt0_0, vr0);
  if (kt0_1 >= 0) vload(kt0_1, vr1);

  // ---- softmax: exact, in registers ----
  float rl[4];
#pragma unroll
  for (int r = 0; r < 4; ++r) {
    const int qi = q0 + 16 * wv + 4 * lg + r;
    float m = -3.0e38f;
#pragma unroll
    for (int ts = 0; ts < NSUB; ++ts) {
      const int ki = q0 - WIN + 16 * ts + lm;
      const bool ok = (ki >= 0) && (ki <= qi) && (ki > qi - WIN);
      float s = ok ? acc[ts][r] : -3.0e38f;
      acc[ts][r] = s;
      m = fmaxf(m, s);
    }
#pragma unroll
    for (int msk = 1; msk < 16; msk <<= 1) m = fmaxf(m, __shfl_xor(m, msk));
    float l = 0.f;
#pragma unroll
    for (int ts = 0; ts < NSUB; ++ts) {
      float p = __expf(acc[ts][r] - m);
      acc[ts][r] = p;
      l += p;
    }
#pragma unroll
    for (int msk = 1; msk < 16; msk <<= 1) l += __shfl_xor(l, msk);
    rl[r] = 1.f / l;
  }

  // ---- write P (bf16, wave-private rows) ----
#pragma unroll
  for (int ts = 0; ts < NSUB; ++ts)
#pragma unroll
    for (int r = 0; r < 4; ++r) {
      const int row = 16 * wv + 4 * lg + r;
      const int col = 16 * ts + lm;
      *(short*)(smem + row * (PSTR * 2) + col * 2) = bf16_of(acc[ts][r]);
    }

  // ---- stage V^T tiles 0,1 ----
  if (kt0_0 >= 0) vwrite(smem + VT0, vr0);
  if (kt0_1 >= 0) vwrite(smem + VT1, vr1);
  __syncthreads();

  // ---- pass 2: O = P V, double-buffered V^T with reg prefetch ----
  f32x4 o[8];
#pragma unroll
  for (int n = 0; n < 8; ++n) o[n] = (f32x4){0.f, 0.f, 0.f, 0.f};

#pragma unroll
  for (int t = 0; t < NTILE; ++t) {
    const int kt0 = q0 - WIN + t * KT;
    const int tp  = t + 2;
    const int ktp = q0 - WIN + tp * KT;
    float4 pre[8];
    if (tp < NTILE && ktp >= 0) vload(ktp, pre);     // issue early
    if (kt0 >= 0) {
      const char* vbuf = smem + ((t & 1) ? VT1 : VT0);
#pragma unroll
      for (int kc = 0; kc < 2; ++kc) {
        const int colb = (16 * wv + lm) * (PSTR * 2) + 128 * t + 64 * kc + 16 * lg;
        bf16x8 pf = *(const bf16x8*)(smem + colb);
#pragma unroll
        for (int n = 0; n < 8; ++n) {
          const int d = 16 * n + lm;
          const int swz = ((d & 7) ^ ((d >> 3) & 7)) << 4;
          bf16x8 vf = *(const bf16x8*)(vbuf + d * 128 + ((64 * kc + 16 * lg) ^ swz));
          o[n] = MFMA(pf, vf, o[n]);
        }
      }
    }
    if (tp < NTILE) {
      __syncthreads();                               // all reads of buf[t&1] done
      if (ktp >= 0) vwrite(smem + ((t & 1) ? VT1 : VT0), pre);
      __syncthreads();                               // buf[tp&1] ready
    }
  }

  // ---- epilogue ----
  float* orow = og + ((size_t)(h * S + q0 + 16 * wv)) * DH;
#pragma unroll
  for (int n = 0; n < 8; ++n)
#pragma unroll
    for (int r = 0; r < 4; ++r)
      orow[(4 * lg + r) * DH + 16 * n + lm] = o[n][r] * rl[r];
}

extern "C" void kernel_launch(void* const* d_in, const int* in_sizes, int n_in,
                              void* d_out, int out_size, void* d_ws, size_t ws_size,
                              hipStream_t stream) {
  const float* q = (const float*)d_in[0];
  const float* k = (const float*)d_in[1];
  const float* v = (const float*)d_in[2];
  float* out = (float*)d_out;
  const int H = 8, D = 128;
  const int S = in_sizes[0] / (H * D);   // 4096
  const int nblk = (S / QB) * H;         // 512, 1-D for XCD swizzle
  lwa3<<<dim3(nblk), 256, 0, stream>>>(q, k, v, out, S);
}

// Round 5
// 129.526 us; speedup vs baseline: 1.0106x; 1.0106x over previous
//
#include <hip/hip_runtime.h>

// LocalWindowAttention B=1 H=8 S=4096 D=128 WIN=256, fp32 in/out.
// QK^T: 3-term bf16 hi/lo split MFMA, K global->reg with 1-ahead prefetch.
// PV: bf16 MFMA, V^T staged in LDS (double-buffered, reg-prefetched).
// Native __bf16 cvt (v_cvt_pk_bf16_f32) throughout. XCD head swizzle.

typedef __bf16 bf16v8 __attribute__((ext_vector_type(8)));
typedef __bf16 bf16x2 __attribute__((ext_vector_type(2)));
typedef float  f32x4  __attribute__((ext_vector_type(4)));

constexpr int QB = 64, DH = 128, WIN = 256, KT = 64;
constexpr int NTILE = 5, NSUB = 20;
constexpr float SCALE = 0.08838834764831844f;  // 1/sqrt(128)

// LDS map (bytes): P [0, 41984) = 64 rows x 328 bf16 (wave-private rows)
//                  V^T buf0 [43008, +16384), buf1 [59392, +16384)
constexpr int PSTR = 328;
constexpr int VT0  = 43008;
constexpr int VT1  = VT0 + 16384;
constexpr int SMEM_BYTES = VT1 + 16384;   // 75776 -> 2 blocks/CU (grid-limited anyway)

union bfu8 { bf16v8 v; bf16x2 p[4]; };

// 8 floats -> hi/lo bf16 split, paired for v_cvt_pk_bf16_f32
__device__ __forceinline__ void cvt_hilo8(const float4& a, const float4& b,
                                          bf16v8& hi, bf16v8& lo) {
  float x[8] = {a.x, a.y, a.z, a.w, b.x, b.y, b.z, b.w};
  bfu8 H, L;
#pragma unroll
  for (int j = 0; j < 4; ++j) {
    float x0 = x[2 * j], x1 = x[2 * j + 1];
    __bf16 h0 = (__bf16)x0, h1 = (__bf16)x1;
    H.p[j] = bf16x2{h0, h1};
    L.p[j] = bf16x2{(__bf16)(x0 - (float)h0), (__bf16)(x1 - (float)h1)};
  }
  hi = H.v; lo = L.v;
}
__device__ __forceinline__ bf16v8 cvt8(const float4& a, const float4& b) {
  float x[8] = {a.x, a.y, a.z, a.w, b.x, b.y, b.z, b.w};
  bfu8 H;
#pragma unroll
  for (int j = 0; j < 4; ++j)
    H.p[j] = bf16x2{(__bf16)x[2 * j], (__bf16)x[2 * j + 1]};
  return H.v;
}
__device__ __forceinline__ unsigned short bfbits(float x) {
  union { __bf16 b; unsigned short u; } c; c.b = (__bf16)x; return c.u;
}
#define MFMA(A, B, C) __builtin_amdgcn_mfma_f32_16x16x32_bf16((A), (B), (C), 0, 0, 0)

__global__ __launch_bounds__(256, 2)
void lwa5(const float* __restrict__ qg, const float* __restrict__ kg,
          const float* __restrict__ vg, float* __restrict__ og, int S) {
  __shared__ __align__(16) char smem[SMEM_BYTES];

  const int bid = blockIdx.x;
  const int h   = bid & 7;              // head -> XCD round-robin (L2 locality)
  const int q0  = (bid >> 3) * QB;
  const int tid = threadIdx.x;
  const int wv  = tid >> 6;
  const int lane = tid & 63;
  const int lg  = lane >> 4;
  const int lm  = lane & 15;

  const float* qgb = qg + (size_t)h * S * DH;
  const float* kgb = kg + (size_t)h * S * DH;
  const float* vgb = vg + (size_t)h * S * DH;

  // ---- Q fragments: global -> reg, scaled, hi/lo split. A-frag row=lm, k=32kc+8lg+j ----
  bf16v8 qhi[4], qlo[4];
  {
    const float* qrow = qgb + (size_t)(q0 + 16 * wv + lm) * DH;
#pragma unroll
    for (int kc = 0; kc < 4; ++kc) {
      const int d0 = 32 * kc + 8 * lg;
      float4 a = *(const float4*)(qrow + d0);
      float4 b = *(const float4*)(qrow + d0 + 4);
      a.x *= SCALE; a.y *= SCALE; a.z *= SCALE; a.w *= SCALE;
      b.x *= SCALE; b.y *= SCALE; b.z *= SCALE; b.w *= SCALE;
      cvt_hilo8(a, b, qhi[kc], qlo[kc]);
    }
  }

  f32x4 acc[NSUB];
#pragma unroll
  for (int t = 0; t < NSUB; ++t) acc[t] = (f32x4){0.f, 0.f, 0.f, 0.f};

  // ---- pass 1: S = Q K^T, flat 16-key subtile loop, 1-ahead K prefetch ----
  // B-frag: key = 16s+lm, d = 32kc+8lg..+7
  float4 kbuf[2][8];
  auto kload = [&](int s, int buf) {
    const int key0 = q0 - WIN + 16 * s;
    if (key0 < 0) return;                        // block-uniform
    const float* kr = kgb + (size_t)(key0 + lm) * DH;
#pragma unroll
    for (int kc = 0; kc < 4; ++kc) {
      kbuf[buf][2 * kc]     = *(const float4*)(kr + 32 * kc + 8 * lg);
      kbuf[buf][2 * kc + 1] = *(const float4*)(kr + 32 * kc + 8 * lg + 4);
    }
  };
  kload(0, 0);
#pragma unroll
  for (int s = 0; s < NSUB; ++s) {
    if (s + 1 < NSUB) kload(s + 1, (s + 1) & 1);  // issue next subtile's loads
    if (q0 - WIN + 16 * s >= 0) {
      f32x4 c = acc[s];
#pragma unroll
      for (int kc = 0; kc < 4; ++kc) {
        bf16v8 kh, kl;
        cvt_hilo8(kbuf[s & 1][2 * kc], kbuf[s & 1][2 * kc + 1], kh, kl);
        c = MFMA(qhi[kc], kh, c);
        c = MFMA(qlo[kc], kh, c);
        c = MFMA(qhi[kc], kl, c);
      }
      acc[s] = c;
    }
  }

  // ---- V staging helpers ----
  const int srow = tid >> 4;          // 0..15
  const int sd0  = (tid & 15) * 8;    // first d of 8
  auto vload = [&](int kt0, float4 r[8]) {
#pragma unroll
    for (int i = 0; i < 4; ++i) {
      const float* p = vgb + (size_t)(kt0 + srow + 16 * i) * DH + sd0;
      r[2 * i]     = *(const float4*)(p);
      r[2 * i + 1] = *(const float4*)(p + 4);
    }
  };
  auto vwrite = [&](char* dst, const float4 r[8]) {
#pragma unroll
    for (int i = 0; i < 4; ++i) {
      const int key = srow + 16 * i;
      float x[8] = {r[2*i].x, r[2*i].y, r[2*i].z, r[2*i].w,
                    r[2*i+1].x, r[2*i+1].y, r[2*i+1].z, r[2*i+1].w};
#pragma unroll
      for (int j = 0; j < 8; ++j) {
        const int d = sd0 + j;
        const int swz = ((d & 7) ^ ((d >> 3) & 7)) << 4;
        *(unsigned short*)(dst + d * 128 + ((key * 2) ^ swz)) = bfbits(x[j]);
      }
    }
  };

  // issue V[0], V[1] global loads now: latency hides under softmax
  const int kt0_0 = q0 - WIN, kt0_1 = q0 - WIN + KT;
  float4 vr0[8], vr1[8];
  if (kt0_0 >= 0) vload(kt0_0, vr0);
  if (kt0_1 >= 0) vload(kt0_1, vr1);

  // ---- softmax: exact, in registers ----
  float rl[4];
#pragma unroll
  for (int r = 0; r < 4; ++r) {
    const int qi = q0 + 16 * wv + 4 * lg + r;
    float m = -3.0e38f;
#pragma unroll
    for (int ts = 0; ts < NSUB; ++ts) {
      const int ki = q0 - WIN + 16 * ts + lm;
      const bool ok = (ki >= 0) && (ki <= qi) && (ki > qi - WIN);
      float s = ok ? acc[ts][r] : -3.0e38f;
      acc[ts][r] = s;
      m = fmaxf(m, s);
    }
#pragma unroll
    for (int msk = 1; msk < 16; msk <<= 1) m = fmaxf(m, __shfl_xor(m, msk));
    float l = 0.f;
#pragma unroll
    for (int ts = 0; ts < NSUB; ++ts) {
      float p = __expf(acc[ts][r] - m);
      acc[ts][r] = p;
      l += p;
    }
#pragma unroll
    for (int msk = 1; msk < 16; msk <<= 1) l += __shfl_xor(l, msk);
    rl[r] = 1.f / l;
  }

  // ---- write P (bf16, wave-private rows) ----
#pragma unroll
  for (int ts = 0; ts < NSUB; ++ts)
#pragma unroll
    for (int r = 0; r < 4; ++r) {
      const int row = 16 * wv + 4 * lg + r;
      const int col = 16 * ts + lm;
      *(unsigned short*)(smem + row * (PSTR * 2) + col * 2) = bfbits(acc[ts][r]);
    }

  // ---- stage V^T tiles 0,1 ----
  if (kt0_0 >= 0) vwrite(smem + VT0, vr0);
  if (kt0_1 >= 0) vwrite(smem + VT1, vr1);
  __syncthreads();

  // ---- pass 2: O = P V, double-buffered V^T with reg prefetch ----
  f32x4 o[8];
#pragma unroll
  for (int n = 0; n < 8; ++n) o[n] = (f32x4){0.f, 0.f, 0.f, 0.f};

#pragma unroll
  for (int t = 0; t < NTILE; ++t) {
    const int kt0 = q0 - WIN + t * KT;
    const int tp  = t + 2;
    const int ktp = q0 - WIN + tp * KT;
    float4 pre[8];
    if (tp < NTILE && ktp >= 0) vload(ktp, pre);     // issue early
    if (kt0 >= 0) {
      const char* vbuf = smem + ((t & 1) ? VT1 : VT0);
#pragma unroll
      for (int kc = 0; kc < 2; ++kc) {
        const int colb = (16 * wv + lm) * (PSTR * 2) + 128 * t + 64 * kc + 16 * lg;
        bf16v8 pf = *(const bf16v8*)(smem + colb);
#pragma unroll
        for (int n = 0; n < 8; ++n) {
          const int d = 16 * n + lm;
          const int swz = ((d & 7) ^ ((d >> 3) & 7)) << 4;
          bf16v8 vf = *(const bf16v8*)(vbuf + d * 128 + ((64 * kc + 16 * lg) ^ swz));
          o[n] = MFMA(pf, vf, o[n]);
        }
      }
    }
    if (tp < NTILE) {
      __syncthreads();                               // all reads of buf[t&1] done
      if (ktp >= 0) vwrite(smem + ((t & 1) ? VT1 : VT0), pre);
      __syncthreads();                               // buf[tp&1] ready
    }
  }

  // ---- epilogue ----
  float* orow = og + ((size_t)(h * S + q0 + 16 * wv)) * DH;
#pragma unroll
  for (int n = 0; n < 8; ++n)
#pragma unroll
    for (int r = 0; r < 4; ++r)
      orow[(4 * lg + r) * DH + 16 * n + lm] = o[n][r] * rl[r];
}

extern "C" void kernel_launch(void* const* d_in, const int* in_sizes, int n_in,
                              void* d_out, int out_size, void* d_ws, size_t ws_size,
                              hipStream_t stream) {
  const float* q = (const float*)d_in[0];
  const float* k = (const float*)d_in[1];
  const float* v = (const float*)d_in[2];
  float* out = (float*)d_out;
  const int H = 8, D = 128;
  const int S = in_sizes[0] / (H * D);   // 4096
  const int nblk = (S / QB) * H;         // 512, 1-D for XCD swizzle
  lwa5<<<dim3(nblk), 256, 0, stream>>>(q, k, v, out, S);
}

// Round 6
// 128.942 us; speedup vs baseline: 1.0151x; 1.0045x over previous
//
#include <hip/hip_runtime.h>

// LocalWindowAttention B=1 H=8 S=4096 D=128 WIN=256, fp32 in/out.
// QB=32, 4 waves: rows split (rg) x window-half split (hf) -> 1024 blocks,
// 16 waves/CU. QK^T: 3-term bf16 hi/lo MFMA, K direct global->reg.
// Softmax: split stats, LDS combine (2 barriers). PV: bf16 MFMA, V B-frags
// gathered direct from global (no V LDS, no pass-2 barriers).

typedef __bf16 bf16v8 __attribute__((ext_vector_type(8)));
typedef __bf16 bf16x2 __attribute__((ext_vector_type(2)));
typedef float  f32x4  __attribute__((ext_vector_type(4)));

constexpr int QB = 32, DH = 128, WIN = 256;
constexpr int HSUB = 9;                    // 16-key subtiles per wave (half window)
constexpr float SCALE = 0.08838834764831844f;  // 1/sqrt(128)

// LDS: P [32 rows][296 bf16] (stride 592B -> 2-way banks) + m/l stats
constexpr int PSTR  = 296;
constexpr int P_BYTES = QB * PSTR * 2;     // 18944
constexpr int MB_OFF  = P_BYTES;           // float mbuf[2][32]
constexpr int LB_OFF  = MB_OFF + 64 * 4;   // float lbuf[2][32]
constexpr int SMEM_BYTES = LB_OFF + 64 * 4;

union bfu8 { bf16v8 v; bf16x2 p[4]; };

__device__ __forceinline__ void cvt_hilo8(const float4& a, const float4& b,
                                          bf16v8& hi, bf16v8& lo) {
  float x[8] = {a.x, a.y, a.z, a.w, b.x, b.y, b.z, b.w};
  bfu8 H, L;
#pragma unroll
  for (int j = 0; j < 4; ++j) {
    float x0 = x[2 * j], x1 = x[2 * j + 1];
    __bf16 h0 = (__bf16)x0, h1 = (__bf16)x1;
    H.p[j] = bf16x2{h0, h1};
    L.p[j] = bf16x2{(__bf16)(x0 - (float)h0), (__bf16)(x1 - (float)h1)};
  }
  hi = H.v; lo = L.v;
}
__device__ __forceinline__ unsigned short bfbits(float x) {
  union { __bf16 b; unsigned short u; } c; c.b = (__bf16)x; return c.u;
}
#define MFMA(A, B, C) __builtin_amdgcn_mfma_f32_16x16x32_bf16((A), (B), (C), 0, 0, 0)

__global__ __launch_bounds__(256, 4)
void lwa6(const float* __restrict__ qg, const float* __restrict__ kg,
          const float* __restrict__ vg, float* __restrict__ og, int S) {
  __shared__ __align__(16) char smem[SMEM_BYTES];

  const int bid = blockIdx.x;
  const int h   = bid & 7;               // head -> XCD round-robin (L2 locality)
  const int q0  = (bid >> 3) * QB;
  const int tid = threadIdx.x;
  const int wv  = tid >> 6;
  const int lane = tid & 63;
  const int lg  = lane >> 4;
  const int lm  = lane & 15;
  const int rg  = wv & 1;                // row group: rows [16rg, 16rg+16)
  const int hf  = wv >> 1;               // window half: subtiles [9hf, 9hf+9)
  const int ts0 = HSUB * hf;

  const float* qgb = qg + (size_t)h * S * DH;
  const float* kgb = kg + (size_t)h * S * DH;
  const float* vgb = vg + (size_t)h * S * DH;

  // ---- Q fragments (rows q0+16rg+lm), scaled, hi/lo split ----
  bf16v8 qhi[4], qlo[4];
  {
    const float* qrow = qgb + (size_t)(q0 + 16 * rg + lm) * DH;
#pragma unroll
    for (int kc = 0; kc < 4; ++kc) {
      float4 a = *(const float4*)(qrow + 32 * kc + 8 * lg);
      float4 b = *(const float4*)(qrow + 32 * kc + 8 * lg + 4);
      a.x *= SCALE; a.y *= SCALE; a.z *= SCALE; a.w *= SCALE;
      b.x *= SCALE; b.y *= SCALE; b.z *= SCALE; b.w *= SCALE;
      cvt_hilo8(a, b, qhi[kc], qlo[kc]);
    }
  }

  f32x4 acc[HSUB];
#pragma unroll
  for (int s = 0; s < HSUB; ++s) acc[s] = (f32x4){0.f, 0.f, 0.f, 0.f};

  // ---- pass 1: this wave's 9 subtiles, K direct global->reg ----
#pragma unroll
  for (int s = 0; s < HSUB; ++s) {
    const int key0 = q0 - WIN + 16 * (ts0 + s);
    if (key0 < 0) continue;              // block-uniform (q0 % 32 == 0)
    const float* kr = kgb + (size_t)(key0 + lm) * DH;
    float4 ka[4], kb_[4];
#pragma unroll
    for (int kc = 0; kc < 4; ++kc) {
      ka[kc]  = *(const float4*)(kr + 32 * kc + 8 * lg);
      kb_[kc] = *(const float4*)(kr + 32 * kc + 8 * lg + 4);
    }
    f32x4 c = acc[s];
#pragma unroll
    for (int kc = 0; kc < 4; ++kc) {
      bf16v8 kh, kl;
      cvt_hilo8(ka[kc], kb_[kc], kh, kl);
      c = MFMA(qhi[kc], kh, c);
      c = MFMA(qlo[kc], kh, c);
      c = MFMA(qhi[kc], kl, c);
    }
    acc[s] = c;
  }

  float* mbuf = (float*)(smem + MB_OFF);   // [2][32]
  float* lbuf = (float*)(smem + LB_OFF);   // [2][32]

  // ---- local max per row, exchange across halves ----
  float mrow[4], rl[4];
#pragma unroll
  for (int r = 0; r < 4; ++r) {
    const int qi = q0 + 16 * rg + 4 * lg + r;
    float m = -3.0e38f;
#pragma unroll
    for (int s = 0; s < HSUB; ++s) {
      const int ki = q0 - WIN + 16 * (ts0 + s) + lm;
      const bool ok = (ki >= 0) && (ki <= qi) && (ki > qi - WIN);
      float v = ok ? acc[s][r] : -3.0e38f;
      acc[s][r] = v;
      m = fmaxf(m, v);
    }
#pragma unroll
    for (int msk = 1; msk < 16; msk <<= 1) m = fmaxf(m, __shfl_xor(m, msk));
    mrow[r] = m;
    if (lm == 0) mbuf[hf * 32 + 16 * rg + 4 * lg + r] = m;
  }
  __syncthreads();
#pragma unroll
  for (int r = 0; r < 4; ++r)
    mrow[r] = fmaxf(mrow[r], mbuf[(1 - hf) * 32 + 16 * rg + 4 * lg + r]);

  // ---- p = exp(s-m), local l, write P (bf16), exchange l ----
#pragma unroll
  for (int r = 0; r < 4; ++r) {
    float l = 0.f;
#pragma unroll
    for (int s = 0; s < HSUB; ++s) {
      float p = __expf(acc[s][r] - mrow[r]);
      acc[s][r] = p;
      l += p;
    }
#pragma unroll
    for (int msk = 1; msk < 16; msk <<= 1) l += __shfl_xor(l, msk);
    if (lm == 0) lbuf[hf * 32 + 16 * rg + 4 * lg + r] = l;
    rl[r] = l;                            // local sum, combined after barrier
    const int row = 16 * rg + 4 * lg + r;
#pragma unroll
    for (int s = 0; s < HSUB; ++s) {
      const int col = 16 * (ts0 + s) + lm;
      *(unsigned short*)(smem + row * (PSTR * 2) + col * 2) = bfbits(acc[s][r]);
    }
  }
  __syncthreads();
#pragma unroll
  for (int r = 0; r < 4; ++r)
    rl[r] = 1.f / (rl[r] + lbuf[(1 - hf) * 32 + 16 * rg + 4 * lg + r]);

  // ---- pass 2: O[rows of rg][d-quarter of hf] = P V, V gathered from global ----
  f32x4 o[4];
#pragma unroll
  for (int n = 0; n < 4; ++n) o[n] = (f32x4){0.f, 0.f, 0.f, 0.f};

#pragma unroll
  for (int kc = 0; kc < 9; ++kc) {        // 32-key chunks over 288-key window
    const int keyb = q0 - WIN + 32 * kc;
    if (keyb < 0) continue;               // block-uniform; P there is 0 anyway
    const bf16v8 pf = *(const bf16v8*)(smem + (16 * rg + lm) * (PSTR * 2) +
                                       (32 * kc + 8 * lg) * 2);
#pragma unroll
    for (int n = 0; n < 4; ++n) {
      const int d = 64 * hf + 16 * n + lm;
      const float* vp = vgb + (size_t)(keyb + 8 * lg) * DH + d;
      float x[8];
#pragma unroll
      for (int j = 0; j < 8; ++j) x[j] = vp[(size_t)j * DH];
      bfu8 V_;
#pragma unroll
      for (int j = 0; j < 4; ++j)
        V_.p[j] = bf16x2{(__bf16)x[2 * j], (__bf16)x[2 * j + 1]};
      o[n] = MFMA(pf, V_.v, o[n]);
    }
  }

  // ---- epilogue: rows 4lg+r of group rg, cols d-quarter of hf ----
  float* ob = og + (size_t)(h * S + q0 + 16 * rg) * DH;
#pragma unroll
  for (int n = 0; n < 4; ++n)
#pragma unroll
    for (int r = 0; r < 4; ++r)
      ob[(4 * lg + r) * DH + 64 * hf + 16 * n + lm] = o[n][r] * rl[r];
}

extern "C" void kernel_launch(void* const* d_in, const int* in_sizes, int n_in,
                              void* d_out, int out_size, void* d_ws, size_t ws_size,
                              hipStream_t stream) {
  const float* q = (const float*)d_in[0];
  const float* k = (const float*)d_in[1];
  const float* v = (const float*)d_in[2];
  float* out = (float*)d_out;
  const int H = 8, D = 128;
  const int S = in_sizes[0] / (H * D);    // 4096
  const int nblk = (S / QB) * H;          // 1024 -> 4 blocks/CU
  lwa6<<<dim3(nblk), 256, 0, stream>>>(q, k, v, out, S);
}